// Round 11
// baseline (307.680 us; speedup 1.0000x reference)
//
#include <hip/hip_runtime.h>
#include <math.h>

#define SQRT2 1.41421356237309515f

typedef __bf16 bf16x8 __attribute__((ext_vector_type(8)));
typedef float f32x4 __attribute__((ext_vector_type(4)));
typedef unsigned short u16x4 __attribute__((ext_vector_type(4)));
typedef unsigned short u16x8 __attribute__((ext_vector_type(8)));

__device__ __forceinline__ unsigned short f2bf(float f) {
    unsigned u = __builtin_bit_cast(unsigned, f);
    u += 0x7fffu + ((u >> 16) & 1u);
    return (unsigned short)(u >> 16);
}

// ---------------- pack helpers (CoG = 32 for all)
__device__ __forceinline__ void pack_cw_elem(
    const float* __restrict__ w, unsigned short* __restrict__ dst,
    int i, int Ci, int KT, float sInv) {
    int cil = i & 31;
    int r = i >> 5;
    int col = r % 32; r /= 32;
    int t = r % 9; r /= 9;
    int c = r % KT, g = r / KT;
    int co = g * 32 + col, ci = c * 32 + cil;
    dst[i] = f2bf(w[((size_t)co * Ci + ci) * 9 + t] * sInv);
}
// blur tap {1,3,3,1} for i in [0,3], 0 outside — branchless, no private array
__device__ __forceinline__ float k1v(int i) {
    return (i == 0 || i == 3) ? 1.f : ((i == 1 || i == 2) ? 3.f : 0.f);
}
__device__ __forceinline__ void pack_fused_elem(
    const float* __restrict__ w, unsigned short* __restrict__ dst,
    int i, int Ci, int KT, float sInv) {
    int cil = i & 31;
    int r = i >> 5;
    int col = r % 32; r /= 32;
    int t = r % 36; r /= 36;
    int c = r % KT, g = r / KT;
    int co = g * 32 + col, ci = c * 32 + cil;
    int p = t / 9, dd = (t % 9) / 3, ee = t % 3;
    int py = p >> 1, px = p & 1;
    const float* wq = w + ((size_t)co * Ci + ci) * 9;
    float acc = 0.f;
#pragma unroll
    for (int rr = 0; rr < 3; ++rr) {
        float ka = k1v(2 * dd + rr - 1 - py);
#pragma unroll
        for (int ss = 0; ss < 3; ++ss) {
            float kb = k1v(2 * ee + ss - 1 - px);
            acc += wq[rr * 3 + ss] * (ka * kb);
        }
    }
    dst[i] = f2bf(acc * sInv * (1.f / 16.f));
}

// ---------------- prep1: pack_all ∪ wsq_all ∪ style (wave-per-output)
__global__ __launch_bounds__(256) void prep1_kernel(
    const float* __restrict__ l0w, const float* __restrict__ l1w,
    const float* __restrict__ l2w, const float* __restrict__ l3w,
    const float* __restrict__ l4w, unsigned short* __restrict__ base,
    float* __restrict__ q, const float* __restrict__ z,
    const float* __restrict__ mw0, const float* __restrict__ mb0,
    const float* __restrict__ mw1, const float* __restrict__ mb1,
    const float* __restrict__ mw2, const float* __restrict__ mb2,
    const float* __restrict__ mw3, const float* __restrict__ mb3,
    const float* __restrict__ mw4, const float* __restrict__ mb4,
    const float* __restrict__ mwf, const float* __restrict__ mbf,
    float* __restrict__ s0, float* __restrict__ s1, float* __restrict__ s2,
    float* __restrict__ s3, float* __restrict__ s4, float* __restrict__ sf) {
    int blk = blockIdx.x, tid = threadIdx.x;
    if (blk < 4392) {
        // ---- pack_all
        const float sInv1152 = 0.02946278254943948f;
        int i = blk * 256 + tid;
        if (i < 294912)       pack_cw_elem(l0w, base, i, 256, 8, 1.f / 48.f);
        else if (i < 368640)  pack_cw_elem(l2w, base + 294912, i - 294912, 128, 4, sInv1152);
        else if (i < 387072)  pack_cw_elem(l4w, base + 368640, i - 368640, 64, 2, 1.f / 24.f);
        else if (i < 976896)  pack_fused_elem(l1w, base + 387072, i - 387072, 128, 4, sInv1152);
        else if (i < 1124352) pack_fused_elem(l3w, base + 976896, i - 976896, 64, 2, 1.f / 24.f);
    } else if (blk < 4640) {
        // ---- wsq_all
        int i = (blk - 4392) * 256 + tid;
        const float* w; float* o; int idx;
        if (i < 32768)      { w = l0w; o = q;          idx = i; }
        else if (i < 49152) { w = l1w; o = q + 32768;  idx = i - 32768; }
        else if (i < 57344) { w = l2w; o = q + 49152;  idx = i - 49152; }
        else if (i < 61440) { w = l3w; o = q + 57344;  idx = i - 57344; }
        else if (i < 63488) { w = l4w; o = q + 61440;  idx = i - 61440; }
        else return;
        const float* wp = w + (size_t)idx * 9;
        float a = 0.f;
#pragma unroll
        for (int t = 0; t < 9; ++t) a += wp[t] * wp[t];
        o[idx] = a;
    } else {
        // ---- style: ONE WAVE per (b,ci) output — coalesced f32x4 row dot.
        int wid = (blk - 4640) * 4 + (tid >> 6);
        int lane = tid & 63;
        const float* mw; const float* mb; float* o; int Ci, idx; float mul = 1.f;
        if (wid < 4096)       { mw = mw0; mb = mb0; o = s0; Ci = 256; idx = wid; }
        else if (wid < 6144)  { mw = mw1; mb = mb1; o = s1; Ci = 128; idx = wid - 4096; }
        else if (wid < 8192)  { mw = mw2; mb = mb2; o = s2; Ci = 128; idx = wid - 6144; }
        else if (wid < 9216)  { mw = mw3; mb = mb3; o = s3; Ci = 64;  idx = wid - 8192; }
        else if (wid < 10240) { mw = mw4; mb = mb4; o = s4; Ci = 64;  idx = wid - 9216; }
        else if (wid < 10752) { mw = mwf; mb = mbf; o = sf; Ci = 32;  idx = wid - 10240;
                                mul = 0.1767766952966369f; }  // 1/sqrt(32)
        else return;
        int b = idx / Ci, ci = idx % Ci;
        const f32x4* zp = (const f32x4*)(z + b * 512);
        const f32x4* wp = (const f32x4*)(mw + (size_t)ci * 512);
        f32x4 a4 = zp[lane] * wp[lane] + zp[lane + 64] * wp[lane + 64];
        float acc = a4[0] + a4[1] + a4[2] + a4[3];
        for (int off = 32; off > 0; off >>= 1) acc += __shfl_down(acc, off);
        if (lane == 0) o[idx] = (acc * 0.04419417382415922f + mb[ci]) * mul;
    }
}

// ---------------- prep2: composite_cl ∪ demod2_all (both depend only on prep1)
__global__ __launch_bounds__(256) void prep2_kernel(
    const float* __restrict__ fg, const float* __restrict__ mask,
    const float* __restrict__ bg, const float* __restrict__ sty0,
    unsigned short* __restrict__ xout,
    const float* __restrict__ q,
    const float* __restrict__ s0, const float* __restrict__ s1,
    const float* __restrict__ s2, const float* __restrict__ s3,
    const float* __restrict__ s4,
    float* __restrict__ d0, float* __restrict__ d1, float* __restrict__ d2,
    float* __restrict__ d3, float* __restrict__ d4) {
    __shared__ unsigned short ldsT[32 * 264];
    int blk = blockIdx.x;
    int t = threadIdx.x;
    if (blk < 512) {
        // ---- composite + transpose to channel-last, x sty0 -> bf16
        int b = blk >> 5, y = blk & 31;
        int x = t & 31, cr = t >> 5;
        const float* sb = sty0 + b * 256;
        float m = 1.f - mask[(b << 10) + (y << 5) + x];
        for (int k = 0; k < 32; ++k) {
            int ci = k * 8 + cr;
            size_t idx = ((size_t)(b * 256 + ci) << 10) + (y << 5) + x;
            float v = fg[idx] + m * bg[idx];
            ldsT[x * 264 + ci] = f2bf(v * sb[ci]);
        }
        __syncthreads();
        int xx = t >> 5, cu = t & 31;
#pragma unroll
        for (int ph = 0; ph < 4; ++ph) {
            int px = ph * 8 + xx;
            u16x8 v = *(const u16x8*)&ldsT[px * 264 + cu * 8];
            *(u16x8*)(xout + (((size_t)(b * 32 + y) * 32 + px) << 8) + cu * 8) = v;
        }
    } else {
        // ---- demod2_all
        int wid = (blk - 512) * 4 + (t >> 6);
        int lane = t & 63;
        const float* qp; const float* s; float* d; int Co, Ci, idx;
        if (wid < 2048)      { qp = q;         s = s0; d = d0; Co = 128; Ci = 256; idx = wid; }
        else if (wid < 4096) { qp = q + 32768; s = s1; d = d1; Co = 128; Ci = 128; idx = wid - 2048; }
        else if (wid < 5120) { qp = q + 49152; s = s2; d = d2; Co = 64;  Ci = 128; idx = wid - 4096; }
        else if (wid < 6144) { qp = q + 57344; s = s3; d = d3; Co = 64;  Ci = 64;  idx = wid - 5120; }
        else if (wid < 6656) { qp = q + 61440; s = s4; d = d4; Co = 32;  Ci = 64;  idx = wid - 6144; }
        else return;
        int b = idx / Co, co = idx % Co;
        const float* wp = qp + (size_t)co * Ci;
        const float* sp = s + b * Ci;
        float acc = 0.f;
        for (int k = lane; k < Ci; k += 64) {
            float sv = sp[k];
            acc += wp[k] * sv * sv;
        }
        for (int off = 32; off > 0; off >>= 1) acc += __shfl_down(acc, off);
        if (lane == 0) d[b * Co + co] = rsqrtf(acc / (float)(Ci * 9) + 1e-8f);
    }
}

// ---------------- MFMA 3x3 conv, channel-last pre-styled input, MT=2 (32 co).
// OUTMODE 0: f32 split-K partial; OUTMODE 1: bf16 epilogue channel-last;
// OUTMODE 3: l4 + fused final 1x1 (32->3) -> d_out NCHW f32.
// ISOLATED A/B vs R10: __launch_bounds__ min-blocks 4 -> 5 (cliff bisection).
// 4 works (FETCH 6.3MB), 6 thrashes (108MB); 5 = 1.25x window, untested.
template <int OUTMODE>
__global__ __launch_bounds__(256, 5) void conv3x3_cl(
    const unsigned short* __restrict__ X, const unsigned short* __restrict__ W,
    const float* __restrict__ demod, const float* __restrict__ bias,
    const float* __restrict__ nextsty, const float* __restrict__ finw,
    const float* __restrict__ ob, void* __restrict__ outv,
    int Ci, int Co, int S, int TPS, int KCH, int cogN) {
    __shared__ unsigned short ldsX[324 * 40];
    const int tid = threadIdx.x;
    const int b = blockIdx.z;
    const int gy_ = blockIdx.y;
    const int ks = gy_ / cogN, cog = gy_ % cogN;
    const int tile = blockIdx.x;
    const int ty0 = (tile / TPS) * 16, tx0 = (tile % TPS) * 16;
    const int KT = Ci >> 5;
    const int wave = tid >> 6, lane = tid & 63, quad = lane >> 4, l16 = lane & 15;

    f32x4 acc[2][4];
#pragma unroll
    for (int mt = 0; mt < 2; ++mt)
#pragma unroll
        for (int nt = 0; nt < 4; ++nt) acc[mt][nt] = (f32x4){0.f, 0.f, 0.f, 0.f};

    for (int cc = 0; cc < KCH; ++cc) {
        const int cg = ks * KCH + cc;
        const int ci0 = cg * 32;
        for (int u = tid; u < 1296; u += 256) {
            int sp = u >> 2, cq = u & 3;
            int y = sp / 18, xx = sp - y * 18;
            int gy = ty0 - 1 + y, gx = tx0 - 1 + xx;
            u16x8 pk = (u16x8){0, 0, 0, 0, 0, 0, 0, 0};
            if ((unsigned)gy < (unsigned)S && (unsigned)gx < (unsigned)S)
                pk = *(const u16x8*)(X + ((size_t)(b * S + gy) * S + gx) * Ci + ci0 + cq * 8);
            *(u16x8*)&ldsX[sp * 40 + cq * 8] = pk;
        }
        __syncthreads();
        const unsigned short* wt = W + (((size_t)cog * KT + cg) * 9) * 1024;
#pragma unroll
        for (int t = 0; t < 9; ++t) {
            const int ty = t / 3, tx = t - ty * 3;
            bf16x8 af[2];
#pragma unroll
            for (int mt = 0; mt < 2; ++mt)
                af[mt] = *(const bf16x8*)(const void*)(wt + t * 1024 + (mt * 16 + l16) * 32 + quad * 8);
#pragma unroll
            for (int nt = 0; nt < 4; ++nt) {
                int sp = (wave * 4 + nt + ty) * 18 + l16 + tx;
                bf16x8 bv = *(const bf16x8*)(const void*)&ldsX[sp * 40 + quad * 8];
#pragma unroll
                for (int mt = 0; mt < 2; ++mt)
                    acc[mt][nt] = __builtin_amdgcn_mfma_f32_16x16x32_bf16(af[mt], bv, acc[mt][nt], 0, 0, 0);
            }
        }
        __syncthreads();
    }
    const int col = tx0 + l16;
    if (OUTMODE == 0) {
        float* out = (float*)outv;
        const size_t PS = (size_t)16 * S * S * Co;
#pragma unroll
        for (int mt = 0; mt < 2; ++mt) {
            int co0 = cog * 32 + mt * 16 + quad * 4;
#pragma unroll
            for (int nt = 0; nt < 4; ++nt) {
                int row = ty0 + wave * 4 + nt;
                *(f32x4*)&out[ks * PS + ((size_t)(b * S + row) * S + col) * Co + co0] = acc[mt][nt];
            }
        }
    } else if (OUTMODE == 1) {
#pragma unroll
        for (int mt = 0; mt < 2; ++mt) {
            int co0 = cog * 32 + mt * 16 + quad * 4;
            f32x4 dm = *(const f32x4*)&demod[b * Co + co0];
            f32x4 bi = *(const f32x4*)&bias[co0];
            f32x4 ns = *(const f32x4*)&nextsty[b * Co + co0];
#pragma unroll
            for (int nt = 0; nt < 4; ++nt) {
                int row = ty0 + wave * 4 + nt;
                size_t base = ((size_t)(b * S + row) * S + col) * Co + co0;
                u16x4 st;
#pragma unroll
                for (int r = 0; r < 4; ++r) {
                    float v = acc[mt][nt][r] * dm[r] + bi[r];
                    v = (v > 0.f ? v : 0.2f * v) * SQRT2 * ns[r];
                    st[r] = f2bf(v);
                }
                *(u16x4*)((unsigned short*)outv + base) = st;
            }
        }
    } else {
        // l4 epilogue + fused final 1x1 (Co=32, cog=0): each l16 column's 4
        // quads x 2 mt hold all 32 channels of pixel (row,col).
        f32x4 dm[2], bi[2], ns[2];
        float fw[3][2][4];
#pragma unroll
        for (int mt = 0; mt < 2; ++mt) {
            int c0 = mt * 16 + quad * 4;
            dm[mt] = *(const f32x4*)&demod[b * Co + c0];
            bi[mt] = *(const f32x4*)&bias[c0];
            ns[mt] = *(const f32x4*)&nextsty[b * Co + c0];
#pragma unroll
            for (int c = 0; c < 3; ++c)
#pragma unroll
                for (int r = 0; r < 4; ++r) fw[c][mt][r] = finw[c * 32 + c0 + r];
        }
        float* out = (float*)outv;
        float ob0 = ob[0], ob1 = ob[1], ob2 = ob[2];
#pragma unroll
        for (int nt = 0; nt < 4; ++nt) {
            int row = ty0 + wave * 4 + nt;
            float p0 = 0.f, p1 = 0.f, p2 = 0.f;
#pragma unroll
            for (int mt = 0; mt < 2; ++mt)
#pragma unroll
                for (int r = 0; r < 4; ++r) {
                    float v = acc[mt][nt][r] * dm[mt][r] + bi[mt][r];
                    v = (v > 0.f ? v : 0.2f * v) * SQRT2 * ns[mt][r];
                    p0 += v * fw[0][mt][r];
                    p1 += v * fw[1][mt][r];
                    p2 += v * fw[2][mt][r];
                }
            p0 += __shfl_xor(p0, 16); p0 += __shfl_xor(p0, 32);
            p1 += __shfl_xor(p1, 16); p1 += __shfl_xor(p1, 32);
            p2 += __shfl_xor(p2, 16); p2 += __shfl_xor(p2, 32);
            if (quad == 0) {
                size_t base = (((size_t)b * 3) << 14) + (row << 7) + col;
                out[base] = p0 + ob0;
                out[base + 16384] = p1 + ob1;
                out[base + 32768] = p2 + ob2;
            }
        }
    }
}

// ---------------- combine split-K partials for l0 (+demod+bias+act+sty1) -> bf16
__global__ __launch_bounds__(256) void combine_l0_kernel(
    const float* __restrict__ P, const float* __restrict__ demod,
    const float* __restrict__ bias, const float* __restrict__ sty1,
    unsigned short* __restrict__ out) {
    int i = blockIdx.x * 256 + threadIdx.x;    // [b][y][x][128]
    int co = i & 127;
    int b = i >> 17;
    float v = P[i] + P[i + (1 << 21)];
    v = v * demod[b * 128 + co] + bias[co];
    v = (v > 0.f ? v : 0.2f * v) * SQRT2 * sty1[b * 128 + co];
    out[i] = f2bf(v);
}

// ---------------- FUSED upconv+blur MFMA, channel-last, parity-per-block, MT=2.
// ISOLATED A/B vs R10: min-blocks 4 -> 5 (cliff bisection; see conv3x3_cl note).
__global__ __launch_bounds__(256, 5) void upblur_cl(
    const unsigned short* __restrict__ X, const unsigned short* __restrict__ EW,
    const float* __restrict__ demod, const float* __restrict__ bias,
    const float* __restrict__ nextsty, unsigned short* __restrict__ out,
    int Ci, int Co, int S, int TPS) {
    __shared__ unsigned short ldsX[324 * 40];
    const int tid = threadIdx.x;
    const int b = blockIdx.z;
    const int cog = blockIdx.y >> 2, p = blockIdx.y & 3;
    const int tile = blockIdx.x;
    const int ty0 = (tile / TPS) * 16, tx0 = (tile % TPS) * 16;
    const int KT = Ci >> 5;
    const int wave = tid >> 6, lane = tid & 63, quad = lane >> 4, l16 = lane & 15;

    f32x4 acc[2][4];
#pragma unroll
    for (int mt = 0; mt < 2; ++mt)
#pragma unroll
        for (int nt = 0; nt < 4; ++nt) acc[mt][nt] = (f32x4){0.f, 0.f, 0.f, 0.f};

    for (int cc = 0; cc < KT; ++cc) {
        const int ci0 = cc * 32;
        for (int u = tid; u < 1296; u += 256) {
            int sp = u >> 2, cq = u & 3;
            int y = sp / 18, xx = sp - y * 18;
            int gy = ty0 - 1 + y, gx = tx0 - 1 + xx;
            u16x8 pk = (u16x8){0, 0, 0, 0, 0, 0, 0, 0};
            if ((unsigned)gy < (unsigned)S && (unsigned)gx < (unsigned)S)
                pk = *(const u16x8*)(X + ((size_t)(b * S + gy) * S + gx) * Ci + ci0 + cq * 8);
            *(u16x8*)&ldsX[sp * 40 + cq * 8] = pk;
        }
        __syncthreads();
        const unsigned short* wt = EW + (((size_t)cog * KT + cc) * 36 + p * 9) * 1024;
#pragma unroll
        for (int t = 0; t < 9; ++t) {
            const int dd = t / 3, ee = t - dd * 3;
            bf16x8 af[2];
#pragma unroll
            for (int mt = 0; mt < 2; ++mt)
                af[mt] = *(const bf16x8*)(const void*)(wt + t * 1024 + (mt * 16 + l16) * 32 + quad * 8);
#pragma unroll
            for (int nt = 0; nt < 4; ++nt) {
                int sp = (wave * 4 + nt + dd) * 18 + l16 + ee;
                bf16x8 bv = *(const bf16x8*)(const void*)&ldsX[sp * 40 + quad * 8];
#pragma unroll
                for (int mt = 0; mt < 2; ++mt)
                    acc[mt][nt] = __builtin_amdgcn_mfma_f32_16x16x32_bf16(af[mt], bv, acc[mt][nt], 0, 0, 0);
            }
        }
        __syncthreads();
    }
    const int S2 = 2 * S;
    const int py = p >> 1, px = p & 1;
    const int Xc = tx0 + l16, ox = 2 * Xc + px;
#pragma unroll
    for (int mt = 0; mt < 2; ++mt) {
        const int co0 = cog * 32 + mt * 16 + quad * 4;
        f32x4 dm = *(const f32x4*)&demod[b * Co + co0];
        f32x4 bi = *(const f32x4*)&bias[co0];
        f32x4 ns = *(const f32x4*)&nextsty[b * Co + co0];
#pragma unroll
        for (int nt = 0; nt < 4; ++nt) {
            int Y = ty0 + wave * 4 + nt, oy = 2 * Y + py;
            u16x4 st;
#pragma unroll
            for (int r = 0; r < 4; ++r) {
                float v = acc[mt][nt][r] * dm[r] + bi[r];
                v = (v > 0.f ? v : 0.2f * v) * SQRT2 * ns[r];
                st[r] = f2bf(v);
            }
            *(u16x4*)(out + ((size_t)(b * S2 + oy) * S2 + ox) * Co + co0) = st;
        }
    }
}

extern "C" void kernel_launch(void* const* d_in, const int* in_sizes, int n_in,
                              void* d_out, int out_size, void* d_ws, size_t ws_size,
                              hipStream_t stream) {
    const float* fg   = (const float*)d_in[0];
    const float* mask = (const float*)d_in[1];
    const float* bg   = (const float*)d_in[2];
    const float* z    = (const float*)d_in[3];
    const float* l0_w = (const float*)d_in[4];
    const float* l0_mw= (const float*)d_in[5];
    const float* l0_mb= (const float*)d_in[6];
    const float* l0_b = (const float*)d_in[7];
    const float* l1_w = (const float*)d_in[8];
    const float* l1_mw= (const float*)d_in[9];
    const float* l1_mb= (const float*)d_in[10];
    const float* l1_b = (const float*)d_in[11];
    const float* l2_w = (const float*)d_in[12];
    const float* l2_mw= (const float*)d_in[13];
    const float* l2_mb= (const float*)d_in[14];
    const float* l2_b = (const float*)d_in[15];
    const float* l3_w = (const float*)d_in[16];
    const float* l3_mw= (const float*)d_in[17];
    const float* l3_mb= (const float*)d_in[18];
    const float* l3_b = (const float*)d_in[19];
    const float* l4_w = (const float*)d_in[20];
    const float* l4_mw= (const float*)d_in[21];
    const float* l4_mb= (const float*)d_in[22];
    const float* l4_b = (const float*)d_in[23];
    const float* fin_w = (const float*)d_in[24];
    const float* fin_mw= (const float*)d_in[25];
    const float* fin_mb= (const float*)d_in[26];
    const float* obias = (const float*)d_in[27];

    float* wsf = (float*)d_ws;
    float* sty0 = wsf + 0;
    float* sty1 = wsf + 4096;
    float* sty2 = wsf + 6144;
    float* sty3 = wsf + 8192;
    float* sty4 = wsf + 9216;
    float* styf = wsf + 10240;   // pre-scaled by 1/sqrt(32)
    float* dm0  = wsf + 10752;
    float* dm1  = wsf + 12800;
    float* dm2  = wsf + 14848;
    float* dm3  = wsf + 15872;
    float* dm4  = wsf + 16896;
    // packed weights: one region, segment offsets match prep1 pack section
    unsigned short* wbase = (unsigned short*)(wsf + 17408);
    unsigned short* wp0 = wbase;            // 294912 sh
    unsigned short* wp2 = wbase + 294912;   // 73728 sh
    unsigned short* wp4 = wbase + 368640;   // 18432 sh
    unsigned short* ew1 = wbase + 387072;   // 589824 sh
    unsigned short* ew3 = wbase + 976896;   // 147456 sh, end 1124352 sh
    // ---- channel-last activations (float offsets), lifetime-audited:
    // X0 [600000, 2697152)    composite bf16 [b][32][32][256]; dead after l0
    // Pb [2697152, 6891456)   l0 split-K f32 [2][b][32][32][128]; dead after combine
    //    (first 63488 floats double as wsq scratch: dead before l0 writes Pbuf)
    // Y0 [6891456, 7940032)   l0 out bf16 [b][32][32][128]; dead after upblur1
    // Z1 [7940032, 12134336)  l1 out bf16 [b][64][64][128]; dead after l2
    // Y2 = alias X0           l2 out bf16 [b][64][64][64]; dead after upblur3
    // Z3 [12134336, 20522944) l3 out bf16 [b][128][128][64]; dead after l4
    unsigned short* X0  = (unsigned short*)(wsf + 600000);
    float* Pbuf = wsf + 2697152;
    unsigned short* Y0  = (unsigned short*)(wsf + 6891456);
    unsigned short* Z1  = (unsigned short*)(wsf + 7940032);
    unsigned short* Y2  = X0;
    unsigned short* Z3  = (unsigned short*)(wsf + 12134336);
    float* wsq = Pbuf;   // 63488 floats, dead before conv l0 runs

    dim3 blk(256);

    // prep1: pack ∪ wsq ∪ style (independent); style = wave-per-output
    prep1_kernel<<<7328, blk, 0, stream>>>(l0_w, l1_w, l2_w, l3_w, l4_w, wbase, wsq, z,
                                           l0_mw, l0_mb, l1_mw, l1_mb, l2_mw, l2_mb,
                                           l3_mw, l3_mb, l4_mw, l4_mb, fin_mw, fin_mb,
                                           sty0, sty1, sty2, sty3, sty4, styf);
    // prep2: composite ∪ demod2 (depend only on prep1)
    prep2_kernel<<<2176, blk, 0, stream>>>(fg, mask, bg, sty0, X0, wsq,
                                           sty0, sty1, sty2, sty3, sty4,
                                           dm0, dm1, dm2, dm3, dm4);

    // l0: conv 256->128 @32, MT=2, split-K=2 -> Pbuf; combine (x sty1) -> Y0
    conv3x3_cl<0><<<dim3(4, 8, 16), blk, 0, stream>>>(X0, wp0, nullptr, nullptr, nullptr, nullptr, nullptr, Pbuf, 256, 128, 32, 2, 4, 4);
    combine_l0_kernel<<<8192, blk, 0, stream>>>(Pbuf, dm0, l0_b, sty1, Y0);

    // l1: fused upconv+blur 128->128, 32->64, parity-split (x sty2) -> Z1
    upblur_cl<<<dim3(4, 16, 16), blk, 0, stream>>>(Y0, ew1, dm1, l1_b, sty2, Z1, 128, 128, 32, 2);

    // l2: conv 128->64 @64, MT=2 (x sty3) -> Y2
    conv3x3_cl<1><<<dim3(16, 2, 16), blk, 0, stream>>>(Z1, wp2, dm2, l2_b, sty3, nullptr, nullptr, Y2, 128, 64, 64, 4, 4, 2);

    // l3: fused upconv+blur 64->64, 64->128, parity-split (x sty4) -> Z3
    upblur_cl<<<dim3(16, 8, 16), blk, 0, stream>>>(Y2, ew3, dm3, l3_b, sty4, Z3, 64, 64, 64, 4);

    // l4: conv 64->32 @128 + fused final 1x1 (x styf/sqrt32) -> d_out
    conv3x3_cl<3><<<dim3(64, 1, 16), blk, 0, stream>>>(Z3, wp4, dm4, l4_b, styf, fin_w, obias, (float*)d_out, 64, 32, 128, 8, 2, 1);
}

// Round 12
// 268.074 us; speedup vs baseline: 1.1477x; 1.1477x over previous
//
#include <hip/hip_runtime.h>
#include <math.h>

#define SQRT2 1.41421356237309515f

typedef __bf16 bf16x8 __attribute__((ext_vector_type(8)));
typedef float f32x4 __attribute__((ext_vector_type(4)));
typedef unsigned short u16x4 __attribute__((ext_vector_type(4)));
typedef unsigned short u16x8 __attribute__((ext_vector_type(8)));

__device__ __forceinline__ unsigned short f2bf(float f) {
    unsigned u = __builtin_bit_cast(unsigned, f);
    u += 0x7fffu + ((u >> 16) & 1u);
    return (unsigned short)(u >> 16);
}

// ---------------- pack helpers (CoG = 32 for all)
__device__ __forceinline__ void pack_cw_elem(
    const float* __restrict__ w, unsigned short* __restrict__ dst,
    int i, int Ci, int KT, float sInv) {
    int cil = i & 31;
    int r = i >> 5;
    int col = r % 32; r /= 32;
    int t = r % 9; r /= 9;
    int c = r % KT, g = r / KT;
    int co = g * 32 + col, ci = c * 32 + cil;
    dst[i] = f2bf(w[((size_t)co * Ci + ci) * 9 + t] * sInv);
}
// blur tap {1,3,3,1} for i in [0,3], 0 outside — branchless, no private array
__device__ __forceinline__ float k1v(int i) {
    return (i == 0 || i == 3) ? 1.f : ((i == 1 || i == 2) ? 3.f : 0.f);
}
__device__ __forceinline__ void pack_fused_elem(
    const float* __restrict__ w, unsigned short* __restrict__ dst,
    int i, int Ci, int KT, float sInv) {
    int cil = i & 31;
    int r = i >> 5;
    int col = r % 32; r /= 32;
    int t = r % 36; r /= 36;
    int c = r % KT, g = r / KT;
    int co = g * 32 + col, ci = c * 32 + cil;
    int p = t / 9, dd = (t % 9) / 3, ee = t % 3;
    int py = p >> 1, px = p & 1;
    const float* wq = w + ((size_t)co * Ci + ci) * 9;
    float acc = 0.f;
#pragma unroll
    for (int rr = 0; rr < 3; ++rr) {
        float ka = k1v(2 * dd + rr - 1 - py);
#pragma unroll
        for (int ss = 0; ss < 3; ++ss) {
            float kb = k1v(2 * ee + ss - 1 - px);
            acc += wq[rr * 3 + ss] * (ka * kb);
        }
    }
    dst[i] = f2bf(acc * sInv * (1.f / 16.f));
}

// ---------------- prep1: pack_all ∪ wsq_all ∪ style (wave-per-output)
__global__ __launch_bounds__(256) void prep1_kernel(
    const float* __restrict__ l0w, const float* __restrict__ l1w,
    const float* __restrict__ l2w, const float* __restrict__ l3w,
    const float* __restrict__ l4w, unsigned short* __restrict__ base,
    float* __restrict__ q, const float* __restrict__ z,
    const float* __restrict__ mw0, const float* __restrict__ mb0,
    const float* __restrict__ mw1, const float* __restrict__ mb1,
    const float* __restrict__ mw2, const float* __restrict__ mb2,
    const float* __restrict__ mw3, const float* __restrict__ mb3,
    const float* __restrict__ mw4, const float* __restrict__ mb4,
    const float* __restrict__ mwf, const float* __restrict__ mbf,
    float* __restrict__ s0, float* __restrict__ s1, float* __restrict__ s2,
    float* __restrict__ s3, float* __restrict__ s4, float* __restrict__ sf) {
    int blk = blockIdx.x, tid = threadIdx.x;
    if (blk < 4392) {
        // ---- pack_all
        const float sInv1152 = 0.02946278254943948f;
        int i = blk * 256 + tid;
        if (i < 294912)       pack_cw_elem(l0w, base, i, 256, 8, 1.f / 48.f);
        else if (i < 368640)  pack_cw_elem(l2w, base + 294912, i - 294912, 128, 4, sInv1152);
        else if (i < 387072)  pack_cw_elem(l4w, base + 368640, i - 368640, 64, 2, 1.f / 24.f);
        else if (i < 976896)  pack_fused_elem(l1w, base + 387072, i - 387072, 128, 4, sInv1152);
        else if (i < 1124352) pack_fused_elem(l3w, base + 976896, i - 976896, 64, 2, 1.f / 24.f);
    } else if (blk < 4640) {
        // ---- wsq_all
        int i = (blk - 4392) * 256 + tid;
        const float* w; float* o; int idx;
        if (i < 32768)      { w = l0w; o = q;          idx = i; }
        else if (i < 49152) { w = l1w; o = q + 32768;  idx = i - 32768; }
        else if (i < 57344) { w = l2w; o = q + 49152;  idx = i - 49152; }
        else if (i < 61440) { w = l3w; o = q + 57344;  idx = i - 57344; }
        else if (i < 63488) { w = l4w; o = q + 61440;  idx = i - 61440; }
        else return;
        const float* wp = w + (size_t)idx * 9;
        float a = 0.f;
#pragma unroll
        for (int t = 0; t < 9; ++t) a += wp[t] * wp[t];
        o[idx] = a;
    } else {
        // ---- style: ONE WAVE per (b,ci) output — coalesced f32x4 row dot.
        int wid = (blk - 4640) * 4 + (tid >> 6);
        int lane = tid & 63;
        const float* mw; const float* mb; float* o; int Ci, idx; float mul = 1.f;
        if (wid < 4096)       { mw = mw0; mb = mb0; o = s0; Ci = 256; idx = wid; }
        else if (wid < 6144)  { mw = mw1; mb = mb1; o = s1; Ci = 128; idx = wid - 4096; }
        else if (wid < 8192)  { mw = mw2; mb = mb2; o = s2; Ci = 128; idx = wid - 6144; }
        else if (wid < 9216)  { mw = mw3; mb = mb3; o = s3; Ci = 64;  idx = wid - 8192; }
        else if (wid < 10240) { mw = mw4; mb = mb4; o = s4; Ci = 64;  idx = wid - 9216; }
        else if (wid < 10752) { mw = mwf; mb = mbf; o = sf; Ci = 32;  idx = wid - 10240;
                                mul = 0.1767766952966369f; }  // 1/sqrt(32)
        else return;
        int b = idx / Ci, ci = idx % Ci;
        const f32x4* zp = (const f32x4*)(z + b * 512);
        const f32x4* wp = (const f32x4*)(mw + (size_t)ci * 512);
        f32x4 a4 = zp[lane] * wp[lane] + zp[lane + 64] * wp[lane + 64];
        float acc = a4[0] + a4[1] + a4[2] + a4[3];
        for (int off = 32; off > 0; off >>= 1) acc += __shfl_down(acc, off);
        if (lane == 0) o[idx] = (acc * 0.04419417382415922f + mb[ci]) * mul;
    }
}

// ---------------- prep2: composite_cl ∪ demod2_all (both depend only on prep1)
__global__ __launch_bounds__(256) void prep2_kernel(
    const float* __restrict__ fg, const float* __restrict__ mask,
    const float* __restrict__ bg, const float* __restrict__ sty0,
    unsigned short* __restrict__ xout,
    const float* __restrict__ q,
    const float* __restrict__ s0, const float* __restrict__ s1,
    const float* __restrict__ s2, const float* __restrict__ s3,
    const float* __restrict__ s4,
    float* __restrict__ d0, float* __restrict__ d1, float* __restrict__ d2,
    float* __restrict__ d3, float* __restrict__ d4) {
    __shared__ unsigned short ldsT[32 * 264];
    int blk = blockIdx.x;
    int t = threadIdx.x;
    if (blk < 512) {
        // ---- composite + transpose to channel-last, x sty0 -> bf16
        int b = blk >> 5, y = blk & 31;
        int x = t & 31, cr = t >> 5;
        const float* sb = sty0 + b * 256;
        float m = 1.f - mask[(b << 10) + (y << 5) + x];
        for (int k = 0; k < 32; ++k) {
            int ci = k * 8 + cr;
            size_t idx = ((size_t)(b * 256 + ci) << 10) + (y << 5) + x;
            float v = fg[idx] + m * bg[idx];
            ldsT[x * 264 + ci] = f2bf(v * sb[ci]);
        }
        __syncthreads();
        int xx = t >> 5, cu = t & 31;
#pragma unroll
        for (int ph = 0; ph < 4; ++ph) {
            int px = ph * 8 + xx;
            u16x8 v = *(const u16x8*)&ldsT[px * 264 + cu * 8];
            *(u16x8*)(xout + (((size_t)(b * 32 + y) * 32 + px) << 8) + cu * 8) = v;
        }
    } else {
        // ---- demod2_all
        int wid = (blk - 512) * 4 + (t >> 6);
        int lane = t & 63;
        const float* qp; const float* s; float* d; int Co, Ci, idx;
        if (wid < 2048)      { qp = q;         s = s0; d = d0; Co = 128; Ci = 256; idx = wid; }
        else if (wid < 4096) { qp = q + 32768; s = s1; d = d1; Co = 128; Ci = 128; idx = wid - 2048; }
        else if (wid < 5120) { qp = q + 49152; s = s2; d = d2; Co = 64;  Ci = 128; idx = wid - 4096; }
        else if (wid < 6144) { qp = q + 57344; s = s3; d = d3; Co = 64;  Ci = 64;  idx = wid - 5120; }
        else if (wid < 6656) { qp = q + 61440; s = s4; d = d4; Co = 32;  Ci = 64;  idx = wid - 6144; }
        else return;
        int b = idx / Co, co = idx % Co;
        const float* wp = qp + (size_t)co * Ci;
        const float* sp = s + b * Ci;
        float acc = 0.f;
        for (int k = lane; k < Ci; k += 64) {
            float sv = sp[k];
            acc += wp[k] * sv * sv;
        }
        for (int off = 32; off > 0; off >>= 1) acc += __shfl_down(acc, off);
        if (lane == 0) d[b * Co + co] = rsqrtf(acc / (float)(Ci * 9) + 1e-8f);
    }
}

// ---------------- MFMA 3x3 conv, channel-last pre-styled input, MT=2 (32 co).
// OUTMODE 0: f32 split-K partial; OUTMODE 1: bf16 epilogue channel-last;
// OUTMODE 3: l4 + fused final 1x1 (32->3) -> d_out NCHW f32.
// __launch_bounds__(256,4): VERIFIED L2-equilibrium ceiling. Bisected:
// 4 blk/CU -> FETCH 6.3MB (93% L2 hit); 5 -> 19MB; 6 -> 108MB (thrash).
template <int OUTMODE>
__global__ __launch_bounds__(256, 4) void conv3x3_cl(
    const unsigned short* __restrict__ X, const unsigned short* __restrict__ W,
    const float* __restrict__ demod, const float* __restrict__ bias,
    const float* __restrict__ nextsty, const float* __restrict__ finw,
    const float* __restrict__ ob, void* __restrict__ outv,
    int Ci, int Co, int S, int TPS, int KCH, int cogN) {
    __shared__ unsigned short ldsX[324 * 40];
    const int tid = threadIdx.x;
    const int b = blockIdx.z;
    const int gy_ = blockIdx.y;
    const int ks = gy_ / cogN, cog = gy_ % cogN;
    const int tile = blockIdx.x;
    const int ty0 = (tile / TPS) * 16, tx0 = (tile % TPS) * 16;
    const int KT = Ci >> 5;
    const int wave = tid >> 6, lane = tid & 63, quad = lane >> 4, l16 = lane & 15;

    f32x4 acc[2][4];
#pragma unroll
    for (int mt = 0; mt < 2; ++mt)
#pragma unroll
        for (int nt = 0; nt < 4; ++nt) acc[mt][nt] = (f32x4){0.f, 0.f, 0.f, 0.f};

    for (int cc = 0; cc < KCH; ++cc) {
        const int cg = ks * KCH + cc;
        const int ci0 = cg * 32;
        for (int u = tid; u < 1296; u += 256) {
            int sp = u >> 2, cq = u & 3;
            int y = sp / 18, xx = sp - y * 18;
            int gy = ty0 - 1 + y, gx = tx0 - 1 + xx;
            u16x8 pk = (u16x8){0, 0, 0, 0, 0, 0, 0, 0};
            if ((unsigned)gy < (unsigned)S && (unsigned)gx < (unsigned)S)
                pk = *(const u16x8*)(X + ((size_t)(b * S + gy) * S + gx) * Ci + ci0 + cq * 8);
            *(u16x8*)&ldsX[sp * 40 + cq * 8] = pk;
        }
        __syncthreads();
        const unsigned short* wt = W + (((size_t)cog * KT + cg) * 9) * 1024;
#pragma unroll
        for (int t = 0; t < 9; ++t) {
            const int ty = t / 3, tx = t - ty * 3;
            bf16x8 af[2];
#pragma unroll
            for (int mt = 0; mt < 2; ++mt)
                af[mt] = *(const bf16x8*)(const void*)(wt + t * 1024 + (mt * 16 + l16) * 32 + quad * 8);
#pragma unroll
            for (int nt = 0; nt < 4; ++nt) {
                int sp = (wave * 4 + nt + ty) * 18 + l16 + tx;
                bf16x8 bv = *(const bf16x8*)(const void*)&ldsX[sp * 40 + quad * 8];
#pragma unroll
                for (int mt = 0; mt < 2; ++mt)
                    acc[mt][nt] = __builtin_amdgcn_mfma_f32_16x16x32_bf16(af[mt], bv, acc[mt][nt], 0, 0, 0);
            }
        }
        __syncthreads();
    }
    const int col = tx0 + l16;
    if (OUTMODE == 0) {
        float* out = (float*)outv;
        const size_t PS = (size_t)16 * S * S * Co;
#pragma unroll
        for (int mt = 0; mt < 2; ++mt) {
            int co0 = cog * 32 + mt * 16 + quad * 4;
#pragma unroll
            for (int nt = 0; nt < 4; ++nt) {
                int row = ty0 + wave * 4 + nt;
                *(f32x4*)&out[ks * PS + ((size_t)(b * S + row) * S + col) * Co + co0] = acc[mt][nt];
            }
        }
    } else if (OUTMODE == 1) {
#pragma unroll
        for (int mt = 0; mt < 2; ++mt) {
            int co0 = cog * 32 + mt * 16 + quad * 4;
            f32x4 dm = *(const f32x4*)&demod[b * Co + co0];
            f32x4 bi = *(const f32x4*)&bias[co0];
            f32x4 ns = *(const f32x4*)&nextsty[b * Co + co0];
#pragma unroll
            for (int nt = 0; nt < 4; ++nt) {
                int row = ty0 + wave * 4 + nt;
                size_t base = ((size_t)(b * S + row) * S + col) * Co + co0;
                u16x4 st;
#pragma unroll
                for (int r = 0; r < 4; ++r) {
                    float v = acc[mt][nt][r] * dm[r] + bi[r];
                    v = (v > 0.f ? v : 0.2f * v) * SQRT2 * ns[r];
                    st[r] = f2bf(v);
                }
                *(u16x4*)((unsigned short*)outv + base) = st;
            }
        }
    } else {
        // l4 epilogue + fused final 1x1 (Co=32, cog=0): each l16 column's 4
        // quads x 2 mt hold all 32 channels of pixel (row,col).
        f32x4 dm[2], bi[2], ns[2];
        float fw[3][2][4];
#pragma unroll
        for (int mt = 0; mt < 2; ++mt) {
            int c0 = mt * 16 + quad * 4;
            dm[mt] = *(const f32x4*)&demod[b * Co + c0];
            bi[mt] = *(const f32x4*)&bias[c0];
            ns[mt] = *(const f32x4*)&nextsty[b * Co + c0];
#pragma unroll
            for (int c = 0; c < 3; ++c)
#pragma unroll
                for (int r = 0; r < 4; ++r) fw[c][mt][r] = finw[c * 32 + c0 + r];
        }
        float* out = (float*)outv;
        float ob0 = ob[0], ob1 = ob[1], ob2 = ob[2];
#pragma unroll
        for (int nt = 0; nt < 4; ++nt) {
            int row = ty0 + wave * 4 + nt;
            float p0 = 0.f, p1 = 0.f, p2 = 0.f;
#pragma unroll
            for (int mt = 0; mt < 2; ++mt)
#pragma unroll
                for (int r = 0; r < 4; ++r) {
                    float v = acc[mt][nt][r] * dm[mt][r] + bi[mt][r];
                    v = (v > 0.f ? v : 0.2f * v) * SQRT2 * ns[mt][r];
                    p0 += v * fw[0][mt][r];
                    p1 += v * fw[1][mt][r];
                    p2 += v * fw[2][mt][r];
                }
            p0 += __shfl_xor(p0, 16); p0 += __shfl_xor(p0, 32);
            p1 += __shfl_xor(p1, 16); p1 += __shfl_xor(p1, 32);
            p2 += __shfl_xor(p2, 16); p2 += __shfl_xor(p2, 32);
            if (quad == 0) {
                size_t base = (((size_t)b * 3) << 14) + (row << 7) + col;
                out[base] = p0 + ob0;
                out[base + 16384] = p1 + ob1;
                out[base + 32768] = p2 + ob2;
            }
        }
    }
}

// ---------------- combine split-K partials for l0 (+demod+bias+act+sty1) -> bf16
__global__ __launch_bounds__(256) void combine_l0_kernel(
    const float* __restrict__ P, const float* __restrict__ demod,
    const float* __restrict__ bias, const float* __restrict__ sty1,
    unsigned short* __restrict__ out) {
    int i = blockIdx.x * 256 + threadIdx.x;    // [b][y][x][128]
    int co = i & 127;
    int b = i >> 17;
    float v = P[i] + P[i + (1 << 21)];
    v = v * demod[b * 128 + co] + bias[co];
    v = (v > 0.f ? v : 0.2f * v) * SQRT2 * sty1[b * 128 + co];
    out[i] = f2bf(v);
}

// ---------------- FUSED upconv+blur MFMA, channel-last, parity-per-block, MT=2.
// __launch_bounds__(256,4): VERIFIED L2-equilibrium ceiling (see conv3x3_cl).
__global__ __launch_bounds__(256, 4) void upblur_cl(
    const unsigned short* __restrict__ X, const unsigned short* __restrict__ EW,
    const float* __restrict__ demod, const float* __restrict__ bias,
    const float* __restrict__ nextsty, unsigned short* __restrict__ out,
    int Ci, int Co, int S, int TPS) {
    __shared__ unsigned short ldsX[324 * 40];
    const int tid = threadIdx.x;
    const int b = blockIdx.z;
    const int cog = blockIdx.y >> 2, p = blockIdx.y & 3;
    const int tile = blockIdx.x;
    const int ty0 = (tile / TPS) * 16, tx0 = (tile % TPS) * 16;
    const int KT = Ci >> 5;
    const int wave = tid >> 6, lane = tid & 63, quad = lane >> 4, l16 = lane & 15;

    f32x4 acc[2][4];
#pragma unroll
    for (int mt = 0; mt < 2; ++mt)
#pragma unroll
        for (int nt = 0; nt < 4; ++nt) acc[mt][nt] = (f32x4){0.f, 0.f, 0.f, 0.f};

    for (int cc = 0; cc < KT; ++cc) {
        const int ci0 = cc * 32;
        for (int u = tid; u < 1296; u += 256) {
            int sp = u >> 2, cq = u & 3;
            int y = sp / 18, xx = sp - y * 18;
            int gy = ty0 - 1 + y, gx = tx0 - 1 + xx;
            u16x8 pk = (u16x8){0, 0, 0, 0, 0, 0, 0, 0};
            if ((unsigned)gy < (unsigned)S && (unsigned)gx < (unsigned)S)
                pk = *(const u16x8*)(X + ((size_t)(b * S + gy) * S + gx) * Ci + ci0 + cq * 8);
            *(u16x8*)&ldsX[sp * 40 + cq * 8] = pk;
        }
        __syncthreads();
        const unsigned short* wt = EW + (((size_t)cog * KT + cc) * 36 + p * 9) * 1024;
#pragma unroll
        for (int t = 0; t < 9; ++t) {
            const int dd = t / 3, ee = t - dd * 3;
            bf16x8 af[2];
#pragma unroll
            for (int mt = 0; mt < 2; ++mt)
                af[mt] = *(const bf16x8*)(const void*)(wt + t * 1024 + (mt * 16 + l16) * 32 + quad * 8);
#pragma unroll
            for (int nt = 0; nt < 4; ++nt) {
                int sp = (wave * 4 + nt + dd) * 18 + l16 + ee;
                bf16x8 bv = *(const bf16x8*)(const void*)&ldsX[sp * 40 + quad * 8];
#pragma unroll
                for (int mt = 0; mt < 2; ++mt)
                    acc[mt][nt] = __builtin_amdgcn_mfma_f32_16x16x32_bf16(af[mt], bv, acc[mt][nt], 0, 0, 0);
            }
        }
        __syncthreads();
    }
    const int S2 = 2 * S;
    const int py = p >> 1, px = p & 1;
    const int Xc = tx0 + l16, ox = 2 * Xc + px;
#pragma unroll
    for (int mt = 0; mt < 2; ++mt) {
        const int co0 = cog * 32 + mt * 16 + quad * 4;
        f32x4 dm = *(const f32x4*)&demod[b * Co + co0];
        f32x4 bi = *(const f32x4*)&bias[co0];
        f32x4 ns = *(const f32x4*)&nextsty[b * Co + co0];
#pragma unroll
        for (int nt = 0; nt < 4; ++nt) {
            int Y = ty0 + wave * 4 + nt, oy = 2 * Y + py;
            u16x4 st;
#pragma unroll
            for (int r = 0; r < 4; ++r) {
                float v = acc[mt][nt][r] * dm[r] + bi[r];
                v = (v > 0.f ? v : 0.2f * v) * SQRT2 * ns[r];
                st[r] = f2bf(v);
            }
            *(u16x4*)(out + ((size_t)(b * S2 + oy) * S2 + ox) * Co + co0) = st;
        }
    }
}

extern "C" void kernel_launch(void* const* d_in, const int* in_sizes, int n_in,
                              void* d_out, int out_size, void* d_ws, size_t ws_size,
                              hipStream_t stream) {
    const float* fg   = (const float*)d_in[0];
    const float* mask = (const float*)d_in[1];
    const float* bg   = (const float*)d_in[2];
    const float* z    = (const float*)d_in[3];
    const float* l0_w = (const float*)d_in[4];
    const float* l0_mw= (const float*)d_in[5];
    const float* l0_mb= (const float*)d_in[6];
    const float* l0_b = (const float*)d_in[7];
    const float* l1_w = (const float*)d_in[8];
    const float* l1_mw= (const float*)d_in[9];
    const float* l1_mb= (const float*)d_in[10];
    const float* l1_b = (const float*)d_in[11];
    const float* l2_w = (const float*)d_in[12];
    const float* l2_mw= (const float*)d_in[13];
    const float* l2_mb= (const float*)d_in[14];
    const float* l2_b = (const float*)d_in[15];
    const float* l3_w = (const float*)d_in[16];
    const float* l3_mw= (const float*)d_in[17];
    const float* l3_mb= (const float*)d_in[18];
    const float* l3_b = (const float*)d_in[19];
    const float* l4_w = (const float*)d_in[20];
    const float* l4_mw= (const float*)d_in[21];
    const float* l4_mb= (const float*)d_in[22];
    const float* l4_b = (const float*)d_in[23];
    const float* fin_w = (const float*)d_in[24];
    const float* fin_mw= (const float*)d_in[25];
    const float* fin_mb= (const float*)d_in[26];
    const float* obias = (const float*)d_in[27];

    float* wsf = (float*)d_ws;
    float* sty0 = wsf + 0;
    float* sty1 = wsf + 4096;
    float* sty2 = wsf + 6144;
    float* sty3 = wsf + 8192;
    float* sty4 = wsf + 9216;
    float* styf = wsf + 10240;   // pre-scaled by 1/sqrt(32)
    float* dm0  = wsf + 10752;
    float* dm1  = wsf + 12800;
    float* dm2  = wsf + 14848;
    float* dm3  = wsf + 15872;
    float* dm4  = wsf + 16896;
    // packed weights: one region, segment offsets match prep1 pack section
    unsigned short* wbase = (unsigned short*)(wsf + 17408);
    unsigned short* wp0 = wbase;            // 294912 sh
    unsigned short* wp2 = wbase + 294912;   // 73728 sh
    unsigned short* wp4 = wbase + 368640;   // 18432 sh
    unsigned short* ew1 = wbase + 387072;   // 589824 sh
    unsigned short* ew3 = wbase + 976896;   // 147456 sh, end 1124352 sh
    // ---- channel-last activations (float offsets), lifetime-audited:
    // X0 [600000, 2697152)    composite bf16 [b][32][32][256]; dead after l0
    // Pb [2697152, 6891456)   l0 split-K f32 [2][b][32][32][128]; dead after combine
    //    (first 63488 floats double as wsq scratch: dead before l0 writes Pbuf)
    // Y0 [6891456, 7940032)   l0 out bf16 [b][32][32][128]; dead after upblur1
    // Z1 [7940032, 12134336)  l1 out bf16 [b][64][64][128]; dead after l2
    // Y2 = alias X0           l2 out bf16 [b][64][64][64]; dead after upblur3
    // Z3 [12134336, 20522944) l3 out bf16 [b][128][128][64]; dead after l4
    unsigned short* X0  = (unsigned short*)(wsf + 600000);
    float* Pbuf = wsf + 2697152;
    unsigned short* Y0  = (unsigned short*)(wsf + 6891456);
    unsigned short* Z1  = (unsigned short*)(wsf + 7940032);
    unsigned short* Y2  = X0;
    unsigned short* Z3  = (unsigned short*)(wsf + 12134336);
    float* wsq = Pbuf;   // 63488 floats, dead before conv l0 runs

    dim3 blk(256);

    // prep1: pack ∪ wsq ∪ style (independent); style = wave-per-output
    prep1_kernel<<<7328, blk, 0, stream>>>(l0_w, l1_w, l2_w, l3_w, l4_w, wbase, wsq, z,
                                           l0_mw, l0_mb, l1_mw, l1_mb, l2_mw, l2_mb,
                                           l3_mw, l3_mb, l4_mw, l4_mb, fin_mw, fin_mb,
                                           sty0, sty1, sty2, sty3, sty4, styf);
    // prep2: composite ∪ demod2 (depend only on prep1)
    prep2_kernel<<<2176, blk, 0, stream>>>(fg, mask, bg, sty0, X0, wsq,
                                           sty0, sty1, sty2, sty3, sty4,
                                           dm0, dm1, dm2, dm3, dm4);

    // l0: conv 256->128 @32, MT=2, split-K=2 -> Pbuf; combine (x sty1) -> Y0
    conv3x3_cl<0><<<dim3(4, 8, 16), blk, 0, stream>>>(X0, wp0, nullptr, nullptr, nullptr, nullptr, nullptr, Pbuf, 256, 128, 32, 2, 4, 4);
    combine_l0_kernel<<<8192, blk, 0, stream>>>(Pbuf, dm0, l0_b, sty1, Y0);

    // l1: fused upconv+blur 128->128, 32->64, parity-split (x sty2) -> Z1
    upblur_cl<<<dim3(4, 16, 16), blk, 0, stream>>>(Y0, ew1, dm1, l1_b, sty2, Z1, 128, 128, 32, 2);

    // l2: conv 128->64 @64, MT=2 (x sty3) -> Y2
    conv3x3_cl<1><<<dim3(16, 2, 16), blk, 0, stream>>>(Z1, wp2, dm2, l2_b, sty3, nullptr, nullptr, Y2, 128, 64, 64, 4, 4, 2);

    // l3: fused upconv+blur 64->64, 64->128, parity-split (x sty4) -> Z3
    upblur_cl<<<dim3(16, 8, 16), blk, 0, stream>>>(Y2, ew3, dm3, l3_b, sty4, Z3, 64, 64, 64, 4);

    // l4: conv 64->32 @128 + fused final 1x1 (x styf/sqrt32) -> d_out
    conv3x3_cl<3><<<dim3(64, 1, 16), blk, 0, stream>>>(Z3, wp4, dm4, l4_b, styf, fin_w, obias, (float*)d_out, 64, 32, 128, 8, 2, 1);
}